// Round 8
// baseline (1016.215 us; speedup 1.0000x reference)
//
#include <hip/hip_runtime.h>
#include <cstdint>
#include <cstddef>

#define B_DIM 16
#define C_DIM 1024
#define N_DIM 2304   // 48*48
#define LDQT 1152    // qt row stride in f16
#define LDE  1088    // eng row stride in f32; attn ld = 2176 f16

typedef _Float16 f16;
typedef _Float16 f16x8 __attribute__((ext_vector_type(8)));
typedef _Float16 f16x4 __attribute__((ext_vector_type(4)));
typedef float f32x4 __attribute__((ext_vector_type(4)));

__device__ __forceinline__ void gload_lds16(const void* g, void* l) {
  __builtin_amdgcn_global_load_lds(
      (const __attribute__((address_space(1))) unsigned int*)g,
      (__attribute__((address_space(3))) unsigned int*)l, 16, 0, 0);
}

// K1: x fp32 [C][N] -> qh f16 [C][N] (ld N_DIM) and qt f16 [N][C] (ld LDQT)
__global__ __launch_bounds__(256)
void k_cast_transpose(const float* __restrict__ x, f16* __restrict__ qh,
                      f16* __restrict__ qt) {
  __shared__ f16 t[64][65];
  const int z = blockIdx.z;
  const int c0 = blockIdx.y * 64, n0 = blockIdx.x * 64;
  const int tid = threadIdx.x;
  const int r = tid >> 2;
  const int cq = (tid & 3) << 4;
  const float* xp = x + ((size_t)z * C_DIM + c0 + r) * N_DIM + n0 + cq;
  float4 v0 = ((const float4*)xp)[0];
  float4 v1 = ((const float4*)xp)[1];
  float4 v2 = ((const float4*)xp)[2];
  float4 v3 = ((const float4*)xp)[3];
  float vv[16] = {v0.x, v0.y, v0.z, v0.w, v1.x, v1.y, v1.z, v1.w,
                  v2.x, v2.y, v2.z, v2.w, v3.x, v3.y, v3.z, v3.w};
  f16 h[16];
#pragma unroll
  for (int j = 0; j < 16; ++j) h[j] = (f16)vv[j];
  f16* qp = qh + ((size_t)z * C_DIM + c0 + r) * N_DIM + n0 + cq;
  ((f16x8*)qp)[0] = *(const f16x8*)&h[0];
  ((f16x8*)qp)[1] = *(const f16x8*)&h[8];
#pragma unroll
  for (int j = 0; j < 16; ++j) t[r][cq + j] = h[j];
  __syncthreads();
  f16 o[16];
#pragma unroll
  for (int j = 0; j < 16; ++j) o[j] = t[cq + j][r];
  f16* tp = qt + ((size_t)z * N_DIM + n0 + r) * LDQT + c0 + cq;
  ((f16x8*)tp)[0] = *(const f16x8*)&o[0];
  ((f16x8*)tp)[1] = *(const f16x8*)&o[8];
}

// K3: one WAVE per row of E (ld LDE): attn = exp(min - e)/sum, f16 in-place.
__global__ __launch_bounds__(256)
void k_softmax(float* __restrict__ eng) {
  const int w = threadIdx.x >> 6, lane = threadIdx.x & 63;
  const int c = blockIdx.x * 4 + w, z = blockIdx.y;
  float* erow = eng + ((size_t)z * C_DIM + c) * LDE;
  float4 v[4];
#pragma unroll
  for (int i = 0; i < 4; ++i) v[i] = ((const float4*)erow)[lane + i * 64];
  float lmin = v[0].x;
#pragma unroll
  for (int i = 0; i < 4; ++i)
    lmin = fminf(lmin, fminf(fminf(v[i].x, v[i].y), fminf(v[i].z, v[i].w)));
#pragma unroll
  for (int s = 32; s > 0; s >>= 1) lmin = fminf(lmin, __shfl_xor(lmin, s, 64));
  float p[16];
  float ls = 0.f;
#pragma unroll
  for (int i = 0; i < 4; ++i) {
    p[i * 4 + 0] = __expf(lmin - v[i].x);
    p[i * 4 + 1] = __expf(lmin - v[i].y);
    p[i * 4 + 2] = __expf(lmin - v[i].z);
    p[i * 4 + 3] = __expf(lmin - v[i].w);
    ls += p[i * 4] + p[i * 4 + 1] + p[i * 4 + 2] + p[i * 4 + 3];
  }
#pragma unroll
  for (int s = 32; s > 0; s >>= 1) ls += __shfl_xor(ls, s, 64);
  const float inv = 1.0f / ls;
#pragma unroll
  for (int i = 0; i < 4; ++i) {
    f16x4 o;
    o.x = (f16)(p[i * 4 + 0] * inv); o.y = (f16)(p[i * 4 + 1] * inv);
    o.z = (f16)(p[i * 4 + 2] * inv); o.w = (f16)(p[i * 4 + 3] * inv);
    *(f16x4*)((f16*)erow + (lane + i * 64) * 4) = o;
  }
}

#define BARR __builtin_amdgcn_s_barrier()
#define SBR __builtin_amdgcn_sched_barrier(0)
#define LGKM(N) asm volatile("s_waitcnt lgkmcnt(" #N ")" ::: "memory")
#define VM8 asm volatile("s_waitcnt vmcnt(8)" ::: "memory")
#define VM0 asm volatile("s_waitcnt vmcnt(0)" ::: "memory")
#define PRIO1 __builtin_amdgcn_s_setprio(1)
#define PRIO0 __builtin_amdgcn_s_setprio(0)

// =================== 256x256 NT GEMM (QK) ===============
#define STA(KT, H) { const int d_ = (KT) & 1;                                  \
    const f16* g_ = Ap + ((H) ? gA1 : gA0) + (size_t)(KT) * 64;                \
    char* l_ = sh + d_ * 32768 + (H) * 8192 + tid * 16;                        \
    gload_lds16(g_, l_); gload_lds16(g_ + 32, l_ + 16384); }

#define STB(KT, H) { const int d_ = (KT) & 1;                                  \
    const f16* g_ = Bp + ((H) ? gB1 : gB0) + (size_t)(KT) * 64;                \
    char* l_ = sh + 65536 + d_ * 32768 + (H) * 8192 + tid * 16;                \
    gload_lds16(g_, l_); gload_lds16(g_ + 32, l_ + 16384); }

#define STAGE(KT) { STA(KT, 0); STA(KT, 1); STB(KT, 0); STB(KT, 1); }

#define RD_A(SET, BASE, MH) _Pragma("unroll") for (int j_ = 0; j_ < 4; ++j_)   \
    _Pragma("unroll") for (int p_ = 0; p_ < 2; ++p_)                           \
      SET[j_ * 2 + p_] =                                                       \
          *(const f16x8*)((BASE) + p_ * 16384 + (MH) * 8192 + j_ * 1024);

#define RD_B(SET, BASE, NH) _Pragma("unroll") for (int i_ = 0; i_ < 2; ++i_)   \
    _Pragma("unroll") for (int p_ = 0; p_ < 2; ++p_)                           \
      SET[i_ * 2 + p_] =                                                       \
          *(const f16x8*)((BASE) + p_ * 16384 + (NH) * 8192 + i_ * 1024);

#define READS(TT) {                                                            \
    const char* Ab_ = sh + ((TT) & 1) * 32768 + aBase;                         \
    const char* Bb_ = sh + 65536 + ((TT) & 1) * 32768 + bBase;                 \
    RD_A(a0r, Ab_, 0); SBR; RD_B(b0r, Bb_, 0); SBR;                            \
    RD_B(b1r, Bb_, 1); SBR; RD_A(a1r, Ab_, 1); SBR; }

#define MMQ(MH, NH, A_, B_) _Pragma("unroll") for (int j_ = 0; j_ < 4; ++j_)   \
    _Pragma("unroll") for (int i_ = 0; i_ < 2; ++i_)                           \
    _Pragma("unroll") for (int k_ = 0; k_ < 2; ++k_)                           \
      acc[(MH) * 4 + j_][(NH) * 2 + i_] =                                      \
          __builtin_amdgcn_mfma_f32_16x16x32_f16(                              \
              A_[j_ * 2 + k_], B_[i_ * 2 + k_],                                \
              acc[(MH) * 4 + j_][(NH) * 2 + i_], 0, 0, 0);

template <int KD, int LDA, int LDB, bool ADDX>
__global__ __launch_bounds__(512, 2)
void k_gemm256(const f16* __restrict__ Ab, const f16* __restrict__ Bb,
               size_t astride, size_t bstride, float* __restrict__ Cb,
               size_t cstride, int ldc, const f16* __restrict__ Xb,
               int nbn, int perb) {
  constexpr int NT = KD / 64;
  static_assert(NT >= 4, "need >= 4 K-tiles");
  __shared__ char sh[131072];
  const int tid = threadIdx.x, lane = tid & 63, wid = tid >> 6;
  const int wm = wid >> 2, wn = wid & 3;

  const int nwg = gridDim.x, orig = blockIdx.x;
  const int qq = nwg >> 3, rr8 = nwg & 7, xcd = orig & 7;
  const int id = (xcd < rr8 ? xcd * (qq + 1) : rr8 * (qq + 1) + (xcd - rr8) * qq)
                 + (orig >> 3);
  const int z = id / perb, t = id - z * perb;
  const int bm = (t / nbn) * 256, bn = (t - (t / nbn) * nbn) * 256;

  const f16* Ap = Ab + z * astride + (size_t)bm * LDA;
  const f16* Bp = Bb + z * bstride + (size_t)bn * LDB;

  const int rq = tid >> 2;
  const int cpr = (tid & 3) ^ ((tid >> 3) & 3);
  const size_t gA0 = (size_t)rq * LDA + cpr * 8;
  const size_t gA1 = gA0 + (size_t)128 * LDA;
  const size_t gB0 = (size_t)rq * LDB + cpr * 8;
  const size_t gB1 = gB0 + (size_t)128 * LDB;

  const int swz = ((lane >> 4) ^ ((lane & 15) >> 1)) & 3;
  const int aBase = (wm * 64 + (lane & 15)) * 64 + swz * 16;
  const int bBase = (wn * 32 + (lane & 15)) * 64 + swz * 16;

  f32x4 acc[8][4] = {};
  f16x8 a0r[8], a1r[8], b0r[4], b1r[4];

  STAGE(0); STAGE(1);
  VM8; BARR; SBR;
  READS(0);

  for (int T = 0; T < NT; ++T) {
    LGKM(12); SBR; PRIO1; MMQ(0, 0, a0r, b0r); PRIO0;
    LGKM(8);  SBR; PRIO1; MMQ(0, 1, a0r, b1r); PRIO0;
    LGKM(0);  SBR; PRIO1; MMQ(1, 1, a1r, b1r);
                          MMQ(1, 0, a1r, b0r); PRIO0;
    if (T < NT - 1) {
      BARR; SBR;
      if (T < NT - 2) { STAGE(T + 2); VM8; }
      else { VM0; }
      BARR; SBR;
      READS(T + 1);
    }
  }

  float* Cp = Cb + z * cstride;
  const f16* Xp = Xb + z * cstride;
#pragma unroll
  for (int mi = 0; mi < 8; ++mi) {
    const int row0 = bm + ((mi < 4) ? wm * 64 + mi * 16
                                    : 128 + wm * 64 + (mi - 4) * 16) +
                     (lane >> 4) * 4;
#pragma unroll
    for (int ni = 0; ni < 4; ++ni) {
      const int col = bn + ((ni < 2) ? wn * 32 + ni * 16
                                     : 128 + wn * 32 + (ni - 2) * 16) +
                      (lane & 15);
#pragma unroll
      for (int j = 0; j < 4; ++j) {
        const size_t idx = (size_t)(row0 + j) * ldc + col;
        float v = acc[mi][ni][j];
        if constexpr (ADDX) v += (float)Xp[idx];
        Cp[idx] = v;
      }
    }
  }
}

// ========= 128x128 NT GEMM (PV): 64KB LDS, 2 resident blocks/CU =========
#define STG128(KT) { const int d_ = (KT) & 1;                                  \
    _Pragma("unroll") for (int g_ = 0; g_ < 4; ++g_)                           \
      gload_lds16(Ap + gSA + (size_t)(g_ & 1) * 64 * LDA + (g_ >> 1) * 32 +    \
                      (size_t)(KT) * 64,                                       \
                  sh + d_ * 16384 + g_ * 4096 + tid * 16);                     \
    _Pragma("unroll") for (int g_ = 0; g_ < 4; ++g_)                           \
      gload_lds16(Bp + gSB + (size_t)(g_ & 1) * 64 * LDB + (g_ >> 1) * 32 +    \
                      (size_t)(KT) * 64,                                       \
                  sh + 32768 + d_ * 16384 + g_ * 4096 + tid * 16); }

#define READS128(TT) {                                                         \
    const char* A_ = sh + ((TT) & 1) * 16384;                                  \
    const char* B_ = sh + 32768 + ((TT) & 1) * 16384;                          \
    _Pragma("unroll") for (int m_ = 0; m_ < 2; ++m_)                           \
    _Pragma("unroll") for (int p_ = 0; p_ < 2; ++p_)                           \
      a[m_ * 2 + p_] = *(const f16x8*)(A_ + p_ * 8192 + aBase + m_ * 1024);    \
    SBR;                                                                       \
    _Pragma("unroll") for (int n_ = 0; n_ < 2; ++n_)                           \
    _Pragma("unroll") for (int p_ = 0; p_ < 2; ++p_)                           \
      b[n_ * 2 + p_] = *(const f16x8*)(B_ + p_ * 8192 + bBase + n_ * 1024);    \
    SBR;                                                                       \
    _Pragma("unroll") for (int n_ = 0; n_ < 2; ++n_)                           \
    _Pragma("unroll") for (int p_ = 0; p_ < 2; ++p_)                           \
      b[4 + n_ * 2 + p_] =                                                     \
          *(const f16x8*)(B_ + p_ * 8192 + bBase + (2 + n_) * 1024);           \
    SBR;                                                                       \
    _Pragma("unroll") for (int m_ = 0; m_ < 2; ++m_)                           \
    _Pragma("unroll") for (int p_ = 0; p_ < 2; ++p_)                           \
      a[4 + m_ * 2 + p_] =                                                     \
          *(const f16x8*)(A_ + p_ * 8192 + aBase + (2 + m_) * 1024);           \
    SBR; }

#define MMQ128(MH, NH) _Pragma("unroll") for (int j_ = 0; j_ < 2; ++j_)        \
    _Pragma("unroll") for (int i_ = 0; i_ < 2; ++i_)                           \
    _Pragma("unroll") for (int k_ = 0; k_ < 2; ++k_)                           \
      acc[(MH) * 2 + j_][(NH) * 2 + i_] =                                      \
          __builtin_amdgcn_mfma_f32_16x16x32_f16(                              \
              a[((MH) * 2 + j_) * 2 + k_], b[((NH) * 2 + i_) * 2 + k_],        \
              acc[(MH) * 2 + j_][(NH) * 2 + i_], 0, 0, 0);

template <int KD, int LDA, int LDB>
__global__ __launch_bounds__(256, 2)
void k_gemm128(const f16* __restrict__ Ab, const f16* __restrict__ Bb,
               size_t astride, size_t bstride, float* __restrict__ Cb,
               size_t cstride, int ldc, const f16* __restrict__ Xb,
               int nbm, int perb) {
  constexpr int NT = KD / 64;
  static_assert(NT >= 4, "need >= 4 K-tiles");
  __shared__ char sh[65536];
  const int tid = threadIdx.x, lane = tid & 63, wid = tid >> 6;
  const int wm = wid >> 1, wn = wid & 1;

  const int nwg = gridDim.x, orig = blockIdx.x;
  const int qq = nwg >> 3, rr8 = nwg & 7, xcd = orig & 7;
  const int id = (xcd < rr8 ? xcd * (qq + 1) : rr8 * (qq + 1) + (xcd - rr8) * qq)
                 + (orig >> 3);
  const int z = id / perb, t = id - z * perb;
  const int bm = (t % nbm) * 128, bn = (t / nbm) * 128;

  const f16* Ap = Ab + z * astride + (size_t)bm * LDA;
  const f16* Bp = Bb + z * bstride + (size_t)bn * LDB;

  const int rq = tid >> 2;
  const int cs = (tid & 3) ^ ((rq >> 1) & 3);
  const size_t gSA = (size_t)rq * LDA + cs * 8;
  const size_t gSB = (size_t)rq * LDB + cs * 8;

  const int swz = ((lane >> 4) ^ ((lane & 15) >> 1)) & 3;
  const int aBase = (wm * 64 + (lane & 15)) * 64 + swz * 16;
  const int bBase = (wn * 64 + (lane & 15)) * 64 + swz * 16;

  f32x4 acc[4][4] = {};
  f16x8 a[8], b[8];

  STG128(0); STG128(1);
  VM8; BARR; SBR;
  READS128(0);

  for (int T = 0; T < NT; ++T) {
    LGKM(8); SBR; PRIO1; MMQ128(0, 0); PRIO0;
    LGKM(4); SBR; PRIO1; MMQ128(0, 1); PRIO0;
    LGKM(0); SBR; PRIO1; MMQ128(1, 1); MMQ128(1, 0); PRIO0;
    if (T < NT - 1) {
      BARR; SBR;
      if (T < NT - 2) { STG128(T + 2); VM8; }
      else { VM0; }
      BARR; SBR;
      READS128(T + 1);
    }
  }

  float* Cp = Cb + z * cstride;
  const f16* Xp = Xb + z * cstride;
#pragma unroll
  for (int mi = 0; mi < 4; ++mi) {
    const int row0 = bm + wm * 64 + mi * 16 + (lane >> 4) * 4;
#pragma unroll
    for (int ni = 0; ni < 4; ++ni) {
      const int col = bn + wn * 64 + ni * 16 + (lane & 15);
#pragma unroll
      for (int j = 0; j < 4; ++j) {
        const size_t idx = (size_t)(row0 + j) * ldc + col;
        Cp[idx] = acc[mi][ni][j] + (float)Xp[idx];
      }
    }
  }
}

// ======== DIAGNOSTIC variants of k_gemm128 (write to dead scratch) ========
// MODE 0=full, 1=no-stage (READS+MFMA only), 2=stage-only (no READS/MFMA).
// REP repeats the K-loop to amplify per-rep cost into the rocprof top-5.
// z=0 only; no XCD swizzle. Output correctness irrelevant (scratch).
template <int KD, int LDA, int LDB, int MODE, int REP>
__global__ __launch_bounds__(256, 2)
void k_gemm128d(const f16* __restrict__ Ab, const f16* __restrict__ Bb,
                float* __restrict__ Cb, int ldc, const f16* __restrict__ Xb,
                int nbm) {
  constexpr int NT = KD / 64;
  __shared__ char sh[65536];
  const int tid = threadIdx.x, lane = tid & 63, wid = tid >> 6;
  const int wm = wid >> 1, wn = wid & 1;
  const int t = blockIdx.x;
  const int bm = (t % nbm) * 128, bn = (t / nbm) * 128;

  const f16* Ap = Ab + (size_t)bm * LDA;
  const f16* Bp = Bb + (size_t)bn * LDB;

  const int rq = tid >> 2;
  const int cs = (tid & 3) ^ ((rq >> 1) & 3);
  const size_t gSA = (size_t)rq * LDA + cs * 8;
  const size_t gSB = (size_t)rq * LDB + cs * 8;

  const int swz = ((lane >> 4) ^ ((lane & 15) >> 1)) & 3;
  const int aBase = (wm * 64 + (lane & 15)) * 64 + swz * 16;
  const int bBase = (wn * 64 + (lane & 15)) * 64 + swz * 16;

  f32x4 acc[4][4] = {};
  f16x8 a[8], b[8];

  STG128(0); STG128(1);
  if constexpr (MODE == 1) { VM0; BARR; SBR; }
  else { VM8; BARR; SBR; }

  for (int rep = 0; rep < REP; ++rep) {
    if constexpr (MODE != 2) READS128(0);
    for (int T = 0; T < NT; ++T) {
      if constexpr (MODE != 2) {
        LGKM(8); SBR; PRIO1; MMQ128(0, 0); PRIO0;
        LGKM(4); SBR; PRIO1; MMQ128(0, 1); PRIO0;
        LGKM(0); SBR; PRIO1; MMQ128(1, 1); MMQ128(1, 0); PRIO0;
      }
      if (T < NT - 1) {
        BARR; SBR;
        if constexpr (MODE != 1) {
          if (T < NT - 2) { STG128(T + 2); VM8; }
          else { VM0; }
        }
        BARR; SBR;
        if constexpr (MODE != 2) READS128(T + 1);
      }
    }
    BARR;
  }

#pragma unroll
  for (int mi = 0; mi < 4; ++mi) {
    const int row0 = bm + wm * 64 + mi * 16 + (lane >> 4) * 4;
#pragma unroll
    for (int ni = 0; ni < 4; ++ni) {
      const int col = bn + wn * 64 + ni * 16 + (lane & 15);
#pragma unroll
      for (int j = 0; j < 4; ++j) {
        const size_t idx = (size_t)(row0 + j) * ldc + col;
        Cb[idx] = acc[mi][ni][j] + (float)Xb[idx];
      }
    }
  }
}

extern "C" void kernel_launch(void* const* d_in, const int* in_sizes, int n_in,
                              void* d_out, int out_size, void* d_ws,
                              size_t ws_size, hipStream_t stream) {
  const float* x = (const float*)d_in[0];
  float* out = (float*)d_out;
  const size_t qh_b = (size_t)C_DIM * N_DIM * sizeof(f16);
  const size_t qt_b = (size_t)N_DIM * LDQT * sizeof(f16);
  const size_t en_b = (size_t)C_DIM * LDE * sizeof(float);
  const size_t per_batch = qh_b + qt_b + en_b;
  const size_t scratch_b = (size_t)C_DIM * N_DIM * sizeof(float);  // 9.4 MB
  size_t avail = (ws_size > scratch_b) ? (ws_size - scratch_b) : 0;
  int G = (int)(avail / per_batch);
  if (G > B_DIM) G = B_DIM;
  if (G < 1) G = 1;

  f16* qh = (f16*)d_ws;
  f16* qt = qh + (size_t)G * C_DIM * N_DIM;
  float* eng = (float*)(qt + (size_t)G * N_DIM * LDQT);
  float* scr = eng + (size_t)G * C_DIM * LDE;

  for (int b0 = 0; b0 < B_DIM; b0 += G) {
    const int g = (B_DIM - b0 < G) ? (B_DIM - b0) : G;
    const float* xg = x + (size_t)b0 * C_DIM * N_DIM;
    float* og = out + (size_t)b0 * C_DIM * N_DIM;

    k_cast_transpose<<<dim3(N_DIM / 64, C_DIM / 64, g), 256, 0, stream>>>(
        xg, qh, qt);

    k_gemm256<N_DIM, N_DIM, N_DIM, false>
        <<<dim3(16 * g), 512, 0, stream>>>(
            qh, qh, (size_t)C_DIM * N_DIM, (size_t)C_DIM * N_DIM, eng,
            (size_t)C_DIM * LDE, LDE, nullptr, 4, 16);

    k_softmax<<<dim3(C_DIM / 4, g), 256, 0, stream>>>(eng);

    k_gemm128<C_DIM, 2 * LDE, LDQT>
        <<<dim3(144 * g), 256, 0, stream>>>(
            (const f16*)eng, qt, (size_t)C_DIM * 2 * LDE,
            (size_t)N_DIM * LDQT, og, (size_t)C_DIM * N_DIM, N_DIM,
            qh, 8, 144);
  }

  // ---- diagnostics (dead scratch output; z=0 data of last group) ----
  // V0: PV shape, full, solo-block regime
  k_gemm128d<C_DIM, 2 * LDE, LDQT, 0, 16><<<144, 256, 0, stream>>>(
      (const f16*)eng, qt, scr, N_DIM, qh, 8);
  // V1: PV shape, staging stripped
  k_gemm128d<C_DIM, 2 * LDE, LDQT, 1, 48><<<144, 256, 0, stream>>>(
      (const f16*)eng, qt, scr, N_DIM, qh, 8);
  // V2: PV shape, compute stripped
  k_gemm128d<C_DIM, 2 * LDE, LDQT, 2, 24><<<144, 256, 0, stream>>>(
      (const f16*)eng, qt, scr, N_DIM, qh, 8);
  // V5: QK shape (K=2304, A=B=qh) on the 128^2 kernel
  k_gemm128d<N_DIM, N_DIM, N_DIM, 0, 8><<<64, 256, 0, stream>>>(
      qh, qh, scr, C_DIM, qh, 8);
}

// Round 9
// 344.781 us; speedup vs baseline: 2.9474x; 2.9474x over previous
//
#include <hip/hip_runtime.h>
#include <cstdint>
#include <cstddef>

#define B_DIM 16
#define C_DIM 1024
#define N_DIM 2304   // 48*48
#define LDQT 1152    // qt row stride in f16
#define LDE  1088    // eng row stride in f32; attn ld = 2176 f16

typedef _Float16 f16;
typedef _Float16 f16x8 __attribute__((ext_vector_type(8)));
typedef _Float16 f16x4 __attribute__((ext_vector_type(4)));
typedef float f32x4 __attribute__((ext_vector_type(4)));

__device__ __forceinline__ void gload_lds16(const void* g, void* l) {
  __builtin_amdgcn_global_load_lds(
      (const __attribute__((address_space(1))) unsigned int*)g,
      (__attribute__((address_space(3))) unsigned int*)l, 16, 0, 0);
}

// K1: x fp32 [C][N] -> qh f16 [C][N] (ld N_DIM) and qt f16 [N][C] (ld LDQT)
__global__ __launch_bounds__(256)
void k_cast_transpose(const float* __restrict__ x, f16* __restrict__ qh,
                      f16* __restrict__ qt) {
  __shared__ f16 t[64][65];
  const int z = blockIdx.z;
  const int c0 = blockIdx.y * 64, n0 = blockIdx.x * 64;
  const int tid = threadIdx.x;
  const int r = tid >> 2;
  const int cq = (tid & 3) << 4;
  const float* xp = x + ((size_t)z * C_DIM + c0 + r) * N_DIM + n0 + cq;
  float4 v0 = ((const float4*)xp)[0];
  float4 v1 = ((const float4*)xp)[1];
  float4 v2 = ((const float4*)xp)[2];
  float4 v3 = ((const float4*)xp)[3];
  float vv[16] = {v0.x, v0.y, v0.z, v0.w, v1.x, v1.y, v1.z, v1.w,
                  v2.x, v2.y, v2.z, v2.w, v3.x, v3.y, v3.z, v3.w};
  f16 h[16];
#pragma unroll
  for (int j = 0; j < 16; ++j) h[j] = (f16)vv[j];
  f16* qp = qh + ((size_t)z * C_DIM + c0 + r) * N_DIM + n0 + cq;
  ((f16x8*)qp)[0] = *(const f16x8*)&h[0];
  ((f16x8*)qp)[1] = *(const f16x8*)&h[8];
#pragma unroll
  for (int j = 0; j < 16; ++j) t[r][cq + j] = h[j];
  __syncthreads();
  f16 o[16];
#pragma unroll
  for (int j = 0; j < 16; ++j) o[j] = t[cq + j][r];
  f16* tp = qt + ((size_t)z * N_DIM + n0 + r) * LDQT + c0 + cq;
  ((f16x8*)tp)[0] = *(const f16x8*)&o[0];
  ((f16x8*)tp)[1] = *(const f16x8*)&o[8];
}

// K3: one WAVE per row of E (ld LDE): attn = exp(min - e)/sum, f16 in-place.
__global__ __launch_bounds__(256)
void k_softmax(float* __restrict__ eng) {
  const int w = threadIdx.x >> 6, lane = threadIdx.x & 63;
  const int c = blockIdx.x * 4 + w, z = blockIdx.y;
  float* erow = eng + ((size_t)z * C_DIM + c) * LDE;
  float4 v[4];
#pragma unroll
  for (int i = 0; i < 4; ++i) v[i] = ((const float4*)erow)[lane + i * 64];
  float lmin = v[0].x;
#pragma unroll
  for (int i = 0; i < 4; ++i)
    lmin = fminf(lmin, fminf(fminf(v[i].x, v[i].y), fminf(v[i].z, v[i].w)));
#pragma unroll
  for (int s = 32; s > 0; s >>= 1) lmin = fminf(lmin, __shfl_xor(lmin, s, 64));
  float p[16];
  float ls = 0.f;
#pragma unroll
  for (int i = 0; i < 4; ++i) {
    p[i * 4 + 0] = __expf(lmin - v[i].x);
    p[i * 4 + 1] = __expf(lmin - v[i].y);
    p[i * 4 + 2] = __expf(lmin - v[i].z);
    p[i * 4 + 3] = __expf(lmin - v[i].w);
    ls += p[i * 4] + p[i * 4 + 1] + p[i * 4 + 2] + p[i * 4 + 3];
  }
#pragma unroll
  for (int s = 32; s > 0; s >>= 1) ls += __shfl_xor(ls, s, 64);
  const float inv = 1.0f / ls;
#pragma unroll
  for (int i = 0; i < 4; ++i) {
    f16x4 o;
    o.x = (f16)(p[i * 4 + 0] * inv); o.y = (f16)(p[i * 4 + 1] * inv);
    o.z = (f16)(p[i * 4 + 2] * inv); o.w = (f16)(p[i * 4 + 3] * inv);
    *(f16x4*)((f16*)erow + (lane + i * 64) * 4) = o;
  }
}

#define BARR __builtin_amdgcn_s_barrier()
#define SBR __builtin_amdgcn_sched_barrier(0)
#define LGKM(N) asm volatile("s_waitcnt lgkmcnt(" #N ")" ::: "memory")
#define VMN(N) asm volatile("s_waitcnt vmcnt(" #N ")" ::: "memory")
#define VM8 VMN(8)
#define VM0 VMN(0)
#define PRIO1 __builtin_amdgcn_s_setprio(1)
#define PRIO0 __builtin_amdgcn_s_setprio(0)

// =================== 256x256 NT GEMM (QK; unchanged) ===============
#define STA(KT, H) { const int d_ = (KT) & 1;                                  \
    const f16* g_ = Ap + ((H) ? gA1 : gA0) + (size_t)(KT) * 64;                \
    char* l_ = sh + d_ * 32768 + (H) * 8192 + tid * 16;                        \
    gload_lds16(g_, l_); gload_lds16(g_ + 32, l_ + 16384); }

#define STB(KT, H) { const int d_ = (KT) & 1;                                  \
    const f16* g_ = Bp + ((H) ? gB1 : gB0) + (size_t)(KT) * 64;                \
    char* l_ = sh + 65536 + d_ * 32768 + (H) * 8192 + tid * 16;                \
    gload_lds16(g_, l_); gload_lds16(g_ + 32, l_ + 16384); }

#define STAGE(KT) { STA(KT, 0); STA(KT, 1); STB(KT, 0); STB(KT, 1); }

#define RD_A(SET, BASE, MH) _Pragma("unroll") for (int j_ = 0; j_ < 4; ++j_)   \
    _Pragma("unroll") for (int p_ = 0; p_ < 2; ++p_)                           \
      SET[j_ * 2 + p_] =                                                       \
          *(const f16x8*)((BASE) + p_ * 16384 + (MH) * 8192 + j_ * 1024);

#define RD_B(SET, BASE, NH) _Pragma("unroll") for (int i_ = 0; i_ < 2; ++i_)   \
    _Pragma("unroll") for (int p_ = 0; p_ < 2; ++p_)                           \
      SET[i_ * 2 + p_] =                                                       \
          *(const f16x8*)((BASE) + p_ * 16384 + (NH) * 8192 + i_ * 1024);

#define READS(TT) {                                                            \
    const char* Ab_ = sh + ((TT) & 1) * 32768 + aBase;                         \
    const char* Bb_ = sh + 65536 + ((TT) & 1) * 32768 + bBase;                 \
    RD_A(a0r, Ab_, 0); SBR; RD_B(b0r, Bb_, 0); SBR;                            \
    RD_B(b1r, Bb_, 1); SBR; RD_A(a1r, Ab_, 1); SBR; }

#define MMQ(MH, NH, A_, B_) _Pragma("unroll") for (int j_ = 0; j_ < 4; ++j_)   \
    _Pragma("unroll") for (int i_ = 0; i_ < 2; ++i_)                           \
    _Pragma("unroll") for (int k_ = 0; k_ < 2; ++k_)                           \
      acc[(MH) * 4 + j_][(NH) * 2 + i_] =                                      \
          __builtin_amdgcn_mfma_f32_16x16x32_f16(                              \
              A_[j_ * 2 + k_], B_[i_ * 2 + k_],                                \
              acc[(MH) * 4 + j_][(NH) * 2 + i_], 0, 0, 0);

template <int KD, int LDA, int LDB, bool ADDX>
__global__ __launch_bounds__(512, 2)
void k_gemm256(const f16* __restrict__ Ab, const f16* __restrict__ Bb,
               size_t astride, size_t bstride, float* __restrict__ Cb,
               size_t cstride, int ldc, const f16* __restrict__ Xb,
               int nbn, int perb) {
  constexpr int NT = KD / 64;
  static_assert(NT >= 4, "need >= 4 K-tiles");
  __shared__ char sh[131072];
  const int tid = threadIdx.x, lane = tid & 63, wid = tid >> 6;
  const int wm = wid >> 2, wn = wid & 3;

  const int nwg = gridDim.x, orig = blockIdx.x;
  const int qq = nwg >> 3, rr8 = nwg & 7, xcd = orig & 7;
  const int id = (xcd < rr8 ? xcd * (qq + 1) : rr8 * (qq + 1) + (xcd - rr8) * qq)
                 + (orig >> 3);
  const int z = id / perb, t = id - z * perb;
  const int bm = (t / nbn) * 256, bn = (t - (t / nbn) * nbn) * 256;

  const f16* Ap = Ab + z * astride + (size_t)bm * LDA;
  const f16* Bp = Bb + z * bstride + (size_t)bn * LDB;

  const int rq = tid >> 2;
  const int cpr = (tid & 3) ^ ((tid >> 3) & 3);
  const size_t gA0 = (size_t)rq * LDA + cpr * 8;
  const size_t gA1 = gA0 + (size_t)128 * LDA;
  const size_t gB0 = (size_t)rq * LDB + cpr * 8;
  const size_t gB1 = gB0 + (size_t)128 * LDB;

  const int swz = ((lane >> 4) ^ ((lane & 15) >> 1)) & 3;
  const int aBase = (wm * 64 + (lane & 15)) * 64 + swz * 16;
  const int bBase = (wn * 32 + (lane & 15)) * 64 + swz * 16;

  f32x4 acc[8][4] = {};
  f16x8 a0r[8], a1r[8], b0r[4], b1r[4];

  STAGE(0); STAGE(1);
  VM8; BARR; SBR;
  READS(0);

  for (int T = 0; T < NT; ++T) {
    LGKM(12); SBR; PRIO1; MMQ(0, 0, a0r, b0r); PRIO0;
    LGKM(8);  SBR; PRIO1; MMQ(0, 1, a0r, b1r); PRIO0;
    LGKM(0);  SBR; PRIO1; MMQ(1, 1, a1r, b1r);
                          MMQ(1, 0, a1r, b0r); PRIO0;
    if (T < NT - 1) {
      BARR; SBR;
      if (T < NT - 2) { STAGE(T + 2); VM8; }
      else { VM0; }
      BARR; SBR;
      READS(T + 1);
    }
  }

  float* Cp = Cb + z * cstride;
  const f16* Xp = Xb + z * cstride;
#pragma unroll
  for (int mi = 0; mi < 8; ++mi) {
    const int row0 = bm + ((mi < 4) ? wm * 64 + mi * 16
                                    : 128 + wm * 64 + (mi - 4) * 16) +
                     (lane >> 4) * 4;
#pragma unroll
    for (int ni = 0; ni < 4; ++ni) {
      const int col = bn + ((ni < 2) ? wn * 32 + ni * 16
                                     : 128 + wn * 32 + (ni - 2) * 16) +
                      (lane & 15);
#pragma unroll
      for (int j = 0; j < 4; ++j) {
        const size_t idx = (size_t)(row0 + j) * ldc + col;
        float v = acc[mi][ni][j];
        if constexpr (ADDX) v += (float)Xp[idx];
        Cp[idx] = v;
      }
    }
  }
}

// ======= PV: 128x128 NT GEMM, A via LDS (32KB, 2 blocks/CU), B via regs ======
// 4 waves (2x2), wave 64x64. Per K-tile: 8 ds_read_b128 + 16KB A-stage on the
// LDS pipe (~480cy) vs 620cy MFMA -> MFMA-bound. B(T) double-buffered in regs
// (b0r/b1r static ping-pong). Counted waits only:
//   VMN(4) before MFMA(T): B(T) done (A(T+1) stage may still fly)
//   VMN(12) at iter end:   A(T+1) done (12 = B(T+1)8 + A(T+2)4 newer)
// Issue order B-then-A pinned with sched_barrier so vmcnt FIFO math holds.

#define STGA_PV(KT) { const int d_ = (KT) & 1;                                 \
    _Pragma("unroll") for (int g_ = 0; g_ < 4; ++g_)                           \
      gload_lds16(Ap + gSA + (size_t)(g_ & 1) * 64 * LDA + (g_ >> 1) * 32 +    \
                      (size_t)(KT) * 64,                                       \
                  sh + d_ * 16384 + g_ * 4096 + tid * 16); }

#define LDB_PV(KT, BB) _Pragma("unroll") for (int n_ = 0; n_ < 4; ++n_)        \
    _Pragma("unroll") for (int p_ = 0; p_ < 2; ++p_)                           \
      BB[n_ * 2 + p_] = *(const f16x8*)(bq + (size_t)n_ * 16 * LDB +           \
                                        p_ * 32 + (size_t)(KT) * 64);

#define RDA_PV(T) { const char* A_ = sh + ((T) & 1) * 16384;                   \
    _Pragma("unroll") for (int m_ = 0; m_ < 4; ++m_)                           \
    _Pragma("unroll") for (int p_ = 0; p_ < 2; ++p_)                           \
      a[m_ * 2 + p_] = *(const f16x8*)(A_ + p_ * 8192 + aBase + m_ * 1024); }

#define MMQ_PV(MH, BB) _Pragma("unroll") for (int j_ = 0; j_ < 2; ++j_)        \
    _Pragma("unroll") for (int i_ = 0; i_ < 4; ++i_)                           \
    _Pragma("unroll") for (int k_ = 0; k_ < 2; ++k_)                           \
      acc[(MH) * 2 + j_][i_] = __builtin_amdgcn_mfma_f32_16x16x32_f16(         \
          a[((MH) * 2 + j_) * 2 + k_], BB[i_ * 2 + k_],                        \
          acc[(MH) * 2 + j_][i_], 0, 0, 0);

#define ITER_PV(T, BC, BN_) {                                                  \
    RDA_PV(T);                                                                 \
    LGKM(4); if ((T) == NT - 1) { VMN(0); } else { VMN(4); } SBR;              \
    PRIO1; MMQ_PV(0, BC); PRIO0;                                               \
    LGKM(0); SBR; PRIO1; MMQ_PV(1, BC); PRIO0;                                 \
    BARR; SBR;                                                                 \
    if ((T) + 1 < NT) { LDB_PV((T) + 1, BN_); SBR; }                           \
    if ((T) + 2 < NT) { STGA_PV((T) + 2); SBR; VMN(12); }                      \
    else if ((T) + 1 < NT) { VMN(8); }                                         \
    BARR; SBR; }

template <int KD, int LDA, int LDB>
__global__ __launch_bounds__(256, 2)
void k_pv(const f16* __restrict__ Ab, const f16* __restrict__ Bb,
          size_t astride, size_t bstride, float* __restrict__ Cb,
          size_t cstride, int ldc, const f16* __restrict__ Xb,
          int nbm, int perb) {
  constexpr int NT = KD / 64;
  static_assert(NT >= 4 && (NT & 1) == 0, "need even #tiles >= 4");
  __shared__ char sh[32768];
  const int tid = threadIdx.x, lane = tid & 63, wid = tid >> 6;
  const int wm = wid >> 1, wn = wid & 1;

  const int nwg = gridDim.x, orig = blockIdx.x;
  const int qq = nwg >> 3, rr8 = nwg & 7, xcd = orig & 7;
  const int id = (xcd < rr8 ? xcd * (qq + 1) : rr8 * (qq + 1) + (xcd - rr8) * qq)
                 + (orig >> 3);
  const int z = id / perb, t = id - z * perb;
  const int bm = (t % nbm) * 128, bn = (t / nbm) * 128;

  const f16* Ap = Ab + z * astride + (size_t)bm * LDA;
  // per-lane B base: row (col) = bn + wn*64 + (lane&15), k-chunk (lane>>4)*8
  const f16* bq = Bb + z * bstride +
                  (size_t)(bn + wn * 64 + (lane & 15)) * LDB +
                  ((lane >> 4) << 3);

  const int rq = tid >> 2;
  const int cs = (tid & 3) ^ ((rq >> 1) & 3);      // inverse-swizzled chunk
  const size_t gSA = (size_t)rq * LDA + cs * 8;

  const int swz = ((lane >> 4) ^ ((lane & 15) >> 1)) & 3;
  const int aBase = (wm * 64 + (lane & 15)) * 64 + swz * 16;

  f32x4 acc[4][4] = {};
  f16x8 a[8], b0r[8], b1r[8];

  // prologue: A(0)->buf0, A(1)->buf1, B(0)->b0r; drain all once.
  STGA_PV(0); STGA_PV(1); SBR;
  LDB_PV(0, b0r); SBR;
  VMN(0); BARR; SBR;

  for (int TT = 0; TT < NT; TT += 2) {
    ITER_PV(TT, b0r, b1r);
    ITER_PV(TT + 1, b1r, b0r);
  }

  float* Cp = Cb + z * cstride;
  const f16* Xp = Xb + z * cstride;
#pragma unroll
  for (int mi = 0; mi < 4; ++mi) {
    const int row0 = bm + wm * 64 + mi * 16 + (lane >> 4) * 4;
#pragma unroll
    for (int ni = 0; ni < 4; ++ni) {
      const int col = bn + wn * 64 + ni * 16 + (lane & 15);
#pragma unroll
      for (int j = 0; j < 4; ++j) {
        const size_t idx = (size_t)(row0 + j) * ldc + col;
        Cp[idx] = acc[mi][ni][j] + (float)Xp[idx];
      }
    }
  }
}

extern "C" void kernel_launch(void* const* d_in, const int* in_sizes, int n_in,
                              void* d_out, int out_size, void* d_ws,
                              size_t ws_size, hipStream_t stream) {
  const float* x = (const float*)d_in[0];
  float* out = (float*)d_out;
  const size_t qh_b = (size_t)C_DIM * N_DIM * sizeof(f16);
  const size_t qt_b = (size_t)N_DIM * LDQT * sizeof(f16);
  const size_t en_b = (size_t)C_DIM * LDE * sizeof(float);
  const size_t per_batch = qh_b + qt_b + en_b;
  int G = (int)(ws_size / per_batch);
  if (G > B_DIM) G = B_DIM;
  if (G < 1) G = 1;

  f16* qh = (f16*)d_ws;
  f16* qt = qh + (size_t)G * C_DIM * N_DIM;
  float* eng = (float*)(qt + (size_t)G * N_DIM * LDQT);

  for (int b0 = 0; b0 < B_DIM; b0 += G) {
    const int g = (B_DIM - b0 < G) ? (B_DIM - b0) : G;
    const float* xg = x + (size_t)b0 * C_DIM * N_DIM;
    float* og = out + (size_t)b0 * C_DIM * N_DIM;

    k_cast_transpose<<<dim3(N_DIM / 64, C_DIM / 64, g), 256, 0, stream>>>(
        xg, qh, qt);

    // E = qh . qh^T  (M=N=C, K=N_DIM); eng ld = LDE
    k_gemm256<N_DIM, N_DIM, N_DIM, false>
        <<<dim3(16 * g), 512, 0, stream>>>(
            qh, qh, (size_t)C_DIM * N_DIM, (size_t)C_DIM * N_DIM, eng,
            (size_t)C_DIM * LDE, LDE, nullptr, 4, 16);

    // attn = softmax(min - E) f16 in-place; one wave per row
    k_softmax<<<dim3(C_DIM / 4, g), 256, 0, stream>>>(eng);

    // out = attn . qt^T + qh(residual)  (M=C, N=N_DIM, K=C)
    k_pv<C_DIM, 2 * LDE, LDQT>
        <<<dim3(144 * g), 256, 0, stream>>>(
            (const f16*)eng, qt, (size_t)C_DIM * 2 * LDE,
            (size_t)N_DIM * LDQT, og, (size_t)C_DIM * N_DIM, N_DIM,
            qh, 8, 144);
  }
}

// Round 10
// 270.455 us; speedup vs baseline: 3.7574x; 1.2748x over previous
//
#include <hip/hip_runtime.h>
#include <cstdint>
#include <cstddef>

#define B_DIM 16
#define C_DIM 1024
#define N_DIM 2304   // 48*48
#define LDQT 1152    // qt row stride in f16
#define LDE  1088    // eng row stride in f32; attn ld = 2176 f16

typedef _Float16 f16;
typedef _Float16 f16x8 __attribute__((ext_vector_type(8)));
typedef _Float16 f16x4 __attribute__((ext_vector_type(4)));
typedef float f32x4 __attribute__((ext_vector_type(4)));

__device__ __forceinline__ void gload_lds16(const void* g, void* l) {
  __builtin_amdgcn_global_load_lds(
      (const __attribute__((address_space(1))) unsigned int*)g,
      (__attribute__((address_space(3))) unsigned int*)l, 16, 0, 0);
}

// K1: x fp32 [C][N] -> qh f16 [C][N] (ld N_DIM) and qt f16 [N][C] (ld LDQT)
__global__ __launch_bounds__(256)
void k_cast_transpose(const float* __restrict__ x, f16* __restrict__ qh,
                      f16* __restrict__ qt) {
  __shared__ f16 t[64][65];
  const int z = blockIdx.z;
  const int c0 = blockIdx.y * 64, n0 = blockIdx.x * 64;
  const int tid = threadIdx.x;
  const int r = tid >> 2;
  const int cq = (tid & 3) << 4;
  const float* xp = x + ((size_t)z * C_DIM + c0 + r) * N_DIM + n0 + cq;
  float4 v0 = ((const float4*)xp)[0];
  float4 v1 = ((const float4*)xp)[1];
  float4 v2 = ((const float4*)xp)[2];
  float4 v3 = ((const float4*)xp)[3];
  float vv[16] = {v0.x, v0.y, v0.z, v0.w, v1.x, v1.y, v1.z, v1.w,
                  v2.x, v2.y, v2.z, v2.w, v3.x, v3.y, v3.z, v3.w};
  f16 h[16];
#pragma unroll
  for (int j = 0; j < 16; ++j) h[j] = (f16)vv[j];
  f16* qp = qh + ((size_t)z * C_DIM + c0 + r) * N_DIM + n0 + cq;
  ((f16x8*)qp)[0] = *(const f16x8*)&h[0];
  ((f16x8*)qp)[1] = *(const f16x8*)&h[8];
#pragma unroll
  for (int j = 0; j < 16; ++j) t[r][cq + j] = h[j];
  __syncthreads();
  f16 o[16];
#pragma unroll
  for (int j = 0; j < 16; ++j) o[j] = t[cq + j][r];
  f16* tp = qt + ((size_t)z * N_DIM + n0 + r) * LDQT + c0 + cq;
  ((f16x8*)tp)[0] = *(const f16x8*)&o[0];
  ((f16x8*)tp)[1] = *(const f16x8*)&o[8];
}

// K3: one WAVE per row of E (ld LDE): attn = exp(min - e)/sum, f16 in-place.
__global__ __launch_bounds__(256)
void k_softmax(float* __restrict__ eng) {
  const int w = threadIdx.x >> 6, lane = threadIdx.x & 63;
  const int c = blockIdx.x * 4 + w, z = blockIdx.y;
  float* erow = eng + ((size_t)z * C_DIM + c) * LDE;
  float4 v[4];
#pragma unroll
  for (int i = 0; i < 4; ++i) v[i] = ((const float4*)erow)[lane + i * 64];
  float lmin = v[0].x;
#pragma unroll
  for (int i = 0; i < 4; ++i)
    lmin = fminf(lmin, fminf(fminf(v[i].x, v[i].y), fminf(v[i].z, v[i].w)));
#pragma unroll
  for (int s = 32; s > 0; s >>= 1) lmin = fminf(lmin, __shfl_xor(lmin, s, 64));
  float p[16];
  float ls = 0.f;
#pragma unroll
  for (int i = 0; i < 4; ++i) {
    p[i * 4 + 0] = __expf(lmin - v[i].x);
    p[i * 4 + 1] = __expf(lmin - v[i].y);
    p[i * 4 + 2] = __expf(lmin - v[i].z);
    p[i * 4 + 3] = __expf(lmin - v[i].w);
    ls += p[i * 4] + p[i * 4 + 1] + p[i * 4 + 2] + p[i * 4 + 3];
  }
#pragma unroll
  for (int s = 32; s > 0; s >>= 1) ls += __shfl_xor(ls, s, 64);
  const float inv = 1.0f / ls;
#pragma unroll
  for (int i = 0; i < 4; ++i) {
    f16x4 o;
    o.x = (f16)(p[i * 4 + 0] * inv); o.y = (f16)(p[i * 4 + 1] * inv);
    o.z = (f16)(p[i * 4 + 2] * inv); o.w = (f16)(p[i * 4 + 3] * inv);
    *(f16x4*)((f16*)erow + (lane + i * 64) * 4) = o;
  }
}

#define BARR __builtin_amdgcn_s_barrier()
#define LGKM(N) asm volatile("s_waitcnt lgkmcnt(" #N ")" ::: "memory")
#define VMN(N) asm volatile("s_waitcnt vmcnt(" #N ")" ::: "memory")
#define PRIO1 __builtin_amdgcn_s_setprio(1)
#define PRIO0 __builtin_amdgcn_s_setprio(0)

// ================ 256x256 NT GEMM, faithful 8-phase template ================
// 512 thr = 8 waves (2M x 4N), wave tile 128x64, BK=64 (2 k-planes of 32).
// LDS 128KB: A[dbuf=KT&1][plane][256][32] @0, B same @65536; chunk XOR swizzle
// (0-conflict, verified R1-R8). NO sched_barriers in the loop (m141).
// Per iter (K-tile pair u=2i, v=2i+1), 8 phases; per phase:
//   {subtile ds_reads | one half-tile stage (2 gloads)} ; [lgkm(8) if 12 reads]
//   BARR ; lgkm(0) ; setprio1 ; 16 MFMA ; setprio0 ; [vmcnt] ; BARR
// Read pattern per K-tile: ph a: A-r0(8)+B-c0(4), ph b: B-c1(4), ph c: A-r1(8),
// ph d: none.  Stage stream (region-free-time verified):
//   ph1: v.A0  ph2: v.A1  ph3: X.B0  ph4: X.B1  ph5: X.A0  ph6: X.A1
//   ph7: Y.B0  ph8: Y.B1        (X=u+2, Y=u+3)
// vmcnt(4) end-ph4 (v fully landed; X.B in flight) and end-ph8 (X landed;
// Y.B in flight) -- every waited-on load issued >=4 phases earlier.

#define STA(KT, H) { const int d_ = (KT) & 1;                                  \
    const f16* g_ = Ap + ((H) ? gA1 : gA0) + (size_t)(KT) * 64;                \
    char* l_ = sh + d_ * 32768 + (H) * 8192 + tid * 16;                        \
    gload_lds16(g_, l_); gload_lds16(g_ + 32, l_ + 16384); }

#define STB(KT, H) { const int d_ = (KT) & 1;                                  \
    const f16* g_ = Bp + ((H) ? gB1 : gB0) + (size_t)(KT) * 64;                \
    char* l_ = sh + 65536 + d_ * 32768 + (H) * 8192 + tid * 16;                \
    gload_lds16(g_, l_); gload_lds16(g_ + 32, l_ + 16384); }

#define RD_AR0(D) _Pragma("unroll") for (int r_ = 0; r_ < 4; ++r_)             \
    _Pragma("unroll") for (int p_ = 0; p_ < 2; ++p_)                           \
      ar0[r_ * 2 + p_] =                                                       \
          *(const f16x8*)(sh + (D) * 32768 + p_ * 16384 + aoff[r_]);

#define RD_AR1(D) _Pragma("unroll") for (int r_ = 0; r_ < 4; ++r_)             \
    _Pragma("unroll") for (int p_ = 0; p_ < 2; ++p_)                           \
      ar1[r_ * 2 + p_] =                                                       \
          *(const f16x8*)(sh + (D) * 32768 + p_ * 16384 + aoff[4 + r_]);

#define RD_BC0(D) _Pragma("unroll") for (int c_ = 0; c_ < 2; ++c_)             \
    _Pragma("unroll") for (int p_ = 0; p_ < 2; ++p_)                           \
      bc0[c_ * 2 + p_] =                                                       \
          *(const f16x8*)(sh + 65536 + (D) * 32768 + p_ * 16384 + boff[c_]);

#define RD_BC1(D) _Pragma("unroll") for (int c_ = 0; c_ < 2; ++c_)             \
    _Pragma("unroll") for (int p_ = 0; p_ < 2; ++p_)                           \
      bc1[c_ * 2 + p_] =                                                       \
          *(const f16x8*)(sh + 65536 + (D) * 32768 + p_ * 16384 +              \
                          boff[2 + c_]);

#define MM(AF, BF, MH, NH) _Pragma("unroll") for (int r_ = 0; r_ < 4; ++r_)    \
    _Pragma("unroll") for (int c_ = 0; c_ < 2; ++c_)                           \
    _Pragma("unroll") for (int p_ = 0; p_ < 2; ++p_)                           \
      acc[(MH) * 4 + r_][(NH) * 2 + c_] =                                      \
          __builtin_amdgcn_mfma_f32_16x16x32_f16(                              \
              AF[r_ * 2 + p_], BF[c_ * 2 + p_],                                \
              acc[(MH) * 4 + r_][(NH) * 2 + c_], 0, 0, 0);

#define ITER8(u, LAST) {                                                       \
  /* ph1 */ RD_AR0(0); RD_BC0(0); STA((u) + 1, 0); LGKM(8);                    \
  BARR; LGKM(0); PRIO1; MM(ar0, bc0, 0, 0); PRIO0; BARR;                       \
  /* ph2 */ RD_BC1(0); STA((u) + 1, 1);                                        \
  BARR; LGKM(0); PRIO1; MM(ar0, bc1, 0, 1); PRIO0; BARR;                       \
  /* ph3 */ RD_AR1(0); if (!(LAST)) STB((u) + 2, 0);                           \
  BARR; LGKM(0); PRIO1; MM(ar1, bc1, 1, 1); PRIO0; BARR;                       \
  /* ph4 */ if (!(LAST)) STB((u) + 2, 1);                                      \
  BARR; PRIO1; MM(ar1, bc0, 1, 0); PRIO0;                                      \
  if (LAST) { VMN(0); } else { VMN(4); } BARR;                                 \
  /* ph5 */ RD_AR0(1); RD_BC0(1); if (!(LAST)) STA((u) + 2, 0); LGKM(8);       \
  BARR; LGKM(0); PRIO1; MM(ar0, bc0, 0, 0); PRIO0; BARR;                       \
  /* ph6 */ RD_BC1(1); if (!(LAST)) STA((u) + 2, 1);                           \
  BARR; LGKM(0); PRIO1; MM(ar0, bc1, 0, 1); PRIO0; BARR;                       \
  /* ph7 */ RD_AR1(1); if (!(LAST)) STB((u) + 3, 0);                           \
  BARR; LGKM(0); PRIO1; MM(ar1, bc1, 1, 1); PRIO0; BARR;                       \
  /* ph8 */ if (!(LAST)) STB((u) + 3, 1);                                      \
  BARR; PRIO1; MM(ar1, bc0, 1, 0); PRIO0;                                      \
  if (!(LAST)) { VMN(4); } BARR; }

template <int KD, int LDA, int LDB, bool ADDX>
__global__ __launch_bounds__(512, 2)
void k_g8(const f16* __restrict__ Ab, const f16* __restrict__ Bb,
          size_t astride, size_t bstride, float* __restrict__ Cb,
          size_t cstride, int ldc, const f16* __restrict__ Xb,
          int nbn, int perb) {
  constexpr int NT = KD / 64, NI = NT / 2;
  static_assert(KD % 128 == 0 && NT >= 4, "need even #K-tiles >= 4");
  __shared__ char sh[131072];
  const int tid = threadIdx.x, lane = tid & 63, wid = tid >> 6;
  const int wm = wid >> 2, wn = wid & 3;   // 2M x 4N waves

  // bijective XCD swizzle (m204)
  const int nwg = gridDim.x, orig = blockIdx.x;
  const int qq = nwg >> 3, rr8 = nwg & 7, xcd = orig & 7;
  const int id = (xcd < rr8 ? xcd * (qq + 1) : rr8 * (qq + 1) + (xcd - rr8) * qq)
                 + (orig >> 3);
  const int z = id / perb, t = id - z * perb;
  const int bm = (t / nbn) * 256, bn = (t - (t / nbn) * nbn) * 256;

  const f16* Ap = Ab + z * astride + (size_t)bm * LDA;
  const f16* Bp = Bb + z * bstride + (size_t)bn * LDB;

  // staging: thread covers row rq (of a 128-row half), inverse-swizzled chunk
  const int rq = tid >> 2;
  const int cpr = (tid & 3) ^ ((tid >> 3) & 3);
  const size_t gA0 = (size_t)rq * LDA + cpr * 8;
  const size_t gA1 = gA0 + (size_t)128 * LDA;
  const size_t gB0 = (size_t)rq * LDB + cpr * 8;
  const size_t gB1 = gB0 + (size_t)128 * LDB;

  // fragment read offsets (swizzle chunk invariant across frag rows)
  const int swz = ((lane >> 4) ^ ((lane & 15) >> 1)) & 3;
  int aoff[8], boff[4];
#pragma unroll
  for (int r = 0; r < 8; ++r)
    aoff[r] = (wm * 128 + r * 16 + (lane & 15)) * 64 + swz * 16;
#pragma unroll
  for (int c = 0; c < 4; ++c)
    boff[c] = (wn * 64 + c * 16 + (lane & 15)) * 64 + swz * 16;

  f32x4 acc[8][4] = {};
  f16x8 ar0[8], ar1[8], bc0[4], bc1[4];

  // prologue: K0 fully (8 insts) + K1.B (4 insts); K0 landed, K1.B in flight
  STA(0, 0); STA(0, 1); STB(0, 0); STB(0, 1);
  STB(1, 0); STB(1, 1);
  VMN(4); BARR;

  for (int i = 0; i < NI - 1; ++i) { ITER8(2 * i, false); }
  ITER8(NT - 2, true);

  float* Cp = Cb + z * cstride;
  const f16* Xp = Xb + z * cstride;
#pragma unroll
  for (int q = 0; q < 8; ++q) {
    const int row0 = bm + wm * 128 + q * 16 + (lane >> 4) * 4;
#pragma unroll
    for (int ci = 0; ci < 4; ++ci) {
      const int col = bn + wn * 64 + ci * 16 + (lane & 15);
#pragma unroll
      for (int j = 0; j < 4; ++j) {
        const size_t idx = (size_t)(row0 + j) * ldc + col;
        float vv = acc[q][ci][j];
        if constexpr (ADDX) vv += (float)Xp[idx];
        Cp[idx] = vv;
      }
    }
  }
}

extern "C" void kernel_launch(void* const* d_in, const int* in_sizes, int n_in,
                              void* d_out, int out_size, void* d_ws,
                              size_t ws_size, hipStream_t stream) {
  const float* x = (const float*)d_in[0];
  float* out = (float*)d_out;
  const size_t qh_b = (size_t)C_DIM * N_DIM * sizeof(f16);
  const size_t qt_b = (size_t)N_DIM * LDQT * sizeof(f16);
  const size_t en_b = (size_t)C_DIM * LDE * sizeof(float);
  const size_t per_batch = qh_b + qt_b + en_b;
  int G = (int)(ws_size / per_batch);
  if (G > B_DIM) G = B_DIM;
  if (G < 1) G = 1;

  f16* qh = (f16*)d_ws;
  f16* qt = qh + (size_t)G * C_DIM * N_DIM;
  float* eng = (float*)(qt + (size_t)G * N_DIM * LDQT);

  for (int b0 = 0; b0 < B_DIM; b0 += G) {
    const int g = (B_DIM - b0 < G) ? (B_DIM - b0) : G;
    const float* xg = x + (size_t)b0 * C_DIM * N_DIM;
    float* og = out + (size_t)b0 * C_DIM * N_DIM;

    k_cast_transpose<<<dim3(N_DIM / 64, C_DIM / 64, g), 256, 0, stream>>>(
        xg, qh, qt);

    // E = qh . qh^T  (M=N=C=1024, K=2304): 4x4 = 16 tiles/batch
    k_g8<N_DIM, N_DIM, N_DIM, false>
        <<<dim3(16 * g), 512, 0, stream>>>(
            qh, qh, (size_t)C_DIM * N_DIM, (size_t)C_DIM * N_DIM, eng,
            (size_t)C_DIM * LDE, LDE, nullptr, 4, 16);

    // attn = softmax(min - E) f16 in-place; one wave per row
    k_softmax<<<dim3(C_DIM / 4, g), 256, 0, stream>>>(eng);

    // out = attn . qt^T + qh  (M=1024, N=2304, K=1024): 4x9 = 36 tiles/batch
    k_g8<C_DIM, 2 * LDE, LDQT, true>
        <<<dim3(36 * g), 512, 0, stream>>>(
            (const f16*)eng, qt, (size_t)C_DIM * 2 * LDE,
            (size_t)N_DIM * LDQT, og, (size_t)C_DIM * N_DIM, N_DIM,
            qh, 9, 36);
  }
}